// Round 17
// baseline (89.823 us; speedup 1.0000x reference)
//
#include <hip/hip_runtime.h>
#include <math.h>

// Problem constants (match reference setup_inputs)
#define B_N   8192      // samples
#define Z_D   128       // feature dim
#define P_N   93        // proxies
#define NCLS  62        // classes
#define A_N   2730      // anchors: arange(0, 8189, 3)
#define BCAP  256       // class-bucket capacity (max expected ~180)
#define GT_S  96        // GT row stride
#define NPART 683       // kB2 grid; 683 = 16*42 + 11
#define TWO_EPS   2e-6f
#define ZEPS2     (128.0f * 1e-6f * 1e-6f)

#define AT_LD(p)      __hip_atomic_load((p), __ATOMIC_RELAXED, __HIP_MEMORY_SCOPE_AGENT)
#define AT_ST(p, v)   __hip_atomic_store((p), (v), __ATOMIC_RELAXED, __HIP_MEMORY_SCOPE_AGENT)
#define AT_ADDU(p, v) __hip_atomic_fetch_add((p), (v), __ATOMIC_RELAXED, __HIP_MEMORY_SCOPE_AGENT)

typedef short bf16x8 __attribute__((ext_vector_type(8)));
typedef float f32x4 __attribute__((ext_vector_type(4)));

__device__ __forceinline__ float wave_sum(float v) {
#pragma unroll
  for (int off = 1; off < 64; off <<= 1) v += __shfl_xor(v, off, 64);
  return v;
}
__device__ __forceinline__ float wave_min(float v) {
#pragma unroll
  for (int off = 1; off < 64; off <<= 1) v = fminf(v, __shfl_xor(v, off, 64));
  return v;
}
__device__ __forceinline__ unsigned short f2bf(float f) {  // RNE bf16
  const unsigned u = __float_as_uint(f);
  return (unsigned short)((u + 0x7FFFu + ((u >> 16) & 1u)) >> 16);
}
__device__ __forceinline__ unsigned pk2(float lo, float hi) {
  return (unsigned)f2bf(lo) | ((unsigned)f2bf(hi) << 16);
}

// --- kPrep: blocks 0..255 convert z->bf16 + fp32 row stats (8 thr/row);
// blocks 256..317 class buckets; block 318 proxy normalize->bf16 + pp/sp +
// pad rows + ctr init. -------------------------------------------------------
__global__ __launch_bounds__(256) void kPrep(
    const float* __restrict__ z, const int* __restrict__ y_idx,
    const float* __restrict__ prox, const int* __restrict__ y_map,
    unsigned short* __restrict__ zb, unsigned short* __restrict__ pb,
    float* __restrict__ pp, float* __restrict__ sp,
    float* __restrict__ zz, float* __restrict__ sz, float* __restrict__ w,
    int* __restrict__ cnt, int* __restrict__ bkt,
    unsigned int* __restrict__ ctr) {
  __shared__ int lcnt;
  const int b = blockIdx.x, tid = threadIdx.x;
  const int lane = tid & 63, wv = tid >> 6;

  if (b < 256) {
    // 32 rows/block, 8 threads/row, 16 elems/thread (coalesced)
    const int row = b * 32 + (tid >> 3);
    const int p8 = tid & 7;
    const float* __restrict__ src = z + (size_t)row * Z_D + p8 * 16;
    const float4 v0 = *(const float4*)(src + 0);
    const float4 v1 = *(const float4*)(src + 4);
    const float4 v2 = *(const float4*)(src + 8);
    const float4 v3 = *(const float4*)(src + 12);
    float s = v0.x + v0.y + v0.z + v0.w + v1.x + v1.y + v1.z + v1.w +
              v2.x + v2.y + v2.z + v2.w + v3.x + v3.y + v3.z + v3.w;
    float q = v0.x*v0.x + v0.y*v0.y + v0.z*v0.z + v0.w*v0.w +
              v1.x*v1.x + v1.y*v1.y + v1.z*v1.z + v1.w*v1.w +
              v2.x*v2.x + v2.y*v2.y + v2.z*v2.z + v2.w*v2.w +
              v3.x*v3.x + v3.y*v3.y + v3.z*v3.z + v3.w*v3.w;
    uint4 pa, pbv;
    pa.x = pk2(v0.x, v0.y); pa.y = pk2(v0.z, v0.w);
    pa.z = pk2(v1.x, v1.y); pa.w = pk2(v1.z, v1.w);
    pbv.x = pk2(v2.x, v2.y); pbv.y = pk2(v2.z, v2.w);
    pbv.z = pk2(v3.x, v3.y); pbv.w = pk2(v3.z, v3.w);
    uint4* dst = (uint4*)(zb + (size_t)row * Z_D + p8 * 16);
    dst[0] = pa; dst[1] = pbv;
#pragma unroll
    for (int off = 1; off < 8; off <<= 1) {   // 8-lane group reduce
      s += __shfl_xor(s, off, 64);
      q += __shfl_xor(q, off, 64);
    }
    if (p8 == 0) { zz[row] = q; sz[row] = s; w[row] = q - TWO_EPS * s; }
  } else if (b < 256 + NCLS) {
    // P0: class c compacts its sample indices (y_map unique => bijection)
    const int c = b - 256;
    if (tid == 0) lcnt = 0;
    __syncthreads();
    const int ym = y_map[c];
    for (int j = tid; j < B_N; j += 256) {
      if (y_idx[j] == ym) {
        const int pos = atomicAdd(&lcnt, 1);     // LDS atomic
        if (pos < BCAP) bkt[c * BCAP + pos] = j;
      }
    }
    __syncthreads();
    if (tid == 0) cnt[c] = min(lcnt, BCAP);
  } else {
    // proxies: normalize (fp32) -> bf16 rows; pp/sp fp32; pad rows 93..95
    for (int k = wv; k < P_N; k += 4) {
      const float a = prox[k * Z_D + lane];
      const float c = prox[k * Z_D + 64 + lane];
      const float s = wave_sum(a + c);
      const float q = wave_sum(a * a + c * c);
      const float inv = 1.0f / fmaxf(sqrtf(q), 1e-12f);
      pb[k * Z_D + lane] = f2bf(a * inv);
      pb[k * Z_D + 64 + lane] = f2bf(c * inv);
      if (lane == 0) { pp[k] = q * inv * inv; sp[k] = s * inv; }
    }
    if (wv == 0)
      for (int t = lane; t < 3 * Z_D; t += 64) pb[P_N * Z_D + t] = 0;
    if (tid < 17) ctr[tid * 32] = 0u;
  }
}

// --- kGT: GT = zb @ pb^T via bf16 MFMA (fp32 accum). 512 blocks x 1 wave;
// wave = 16-row strip x 96 proxies = 6 tiles x 4 k-steps of 16x16x32.
// Layouts (m89-verified): A m=lane&15,k=quad*8+j; B n=lane&15,k=quad*8+j;
// D col(n)=lane&15, row(m)=quad*4+reg. ---------------------------------------
__global__ __launch_bounds__(64) void kGT(
    const unsigned short* __restrict__ zb, const unsigned short* __restrict__ pb,
    float* __restrict__ GT) {
  const int lane = threadIdx.x & 63;
  const int m = lane & 15, quad = lane >> 4;
  const int j0 = blockIdx.x * 16;
  const unsigned short* __restrict__ zrow = zb + (size_t)(j0 + m) * Z_D;
  bf16x8 af[4];
#pragma unroll
  for (int kb = 0; kb < 4; ++kb)
    af[kb] = *(const bf16x8*)(zrow + kb * 32 + quad * 8);
#pragma unroll
  for (int nt = 0; nt < 6; ++nt) {
    const unsigned short* __restrict__ prow = pb + (size_t)(nt * 16 + m) * Z_D;
    f32x4 acc = {0.0f, 0.0f, 0.0f, 0.0f};
#pragma unroll
    for (int kb = 0; kb < 4; ++kb) {
      const bf16x8 bfr = *(const bf16x8*)(prow + kb * 32 + quad * 8);
      acc = __builtin_amdgcn_mfma_f32_16x16x32_bf16(af[kb], bfr, acc, 0, 0, 0);
    }
#pragma unroll
    for (int r = 0; r < 4; ++r)
      GT[(size_t)(j0 + quad * 4 + r) * GT_S + nt * 16 + m] = acc[r];
  }
}

// --- kB2: EXACT R12-benched champion body (one wave per anchor;
// R10/R11-validated hierarchical finalize). ----------------------------------
__global__ __launch_bounds__(256) void kB2(
    const int* __restrict__ y_idx, const int* __restrict__ y_map,
    const float* __restrict__ pp, const float* __restrict__ sp,
    const float* __restrict__ zz, const float* __restrict__ sz,
    const float* __restrict__ w,
    const int* __restrict__ cnt, const int* __restrict__ bkt,
    const float* __restrict__ GT, float* partial, unsigned int* ctr,
    float* __restrict__ out) {
  __shared__ float lpp[P_N], lsp[P_N];
  __shared__ int lymap[NCLS];
  __shared__ float part[4];
  const int b = blockIdx.x;
  const int tid = threadIdx.x, lane = tid & 63, wv = tid >> 6;
  if (tid < P_N) { lpp[tid] = pp[tid]; lsp[tid] = sp[tid]; }
  if (tid < NCLS) lymap[tid] = y_map[tid];
  __syncthreads();

  const int wid = b * 4 + wv;
  float loss = 0.0f;
  if (wid < A_N) {
    const int i = 3 * wid;
    const int yi = y_idx[i];
    const unsigned long long mm = __ballot(lane < NCLS && lymap[lane] == yi);
    const int cls = __ffsll(mm) - 1;       // unique match (y_map unique)
    const float zzi = zz[i], szi = sz[i];
    const int kB = lane + 64;

    // step a: nearest proxy (argmin, first-index tie-break)
    const float* __restrict__ GTi = GT + (size_t)i * GT_S;
    float v1 = fmaxf(zzi + lpp[lane] - 2.0f * GTi[lane] +
                     TWO_EPS * (szi - lsp[lane]) + ZEPS2, 0.0f);
    int i1 = lane;
    if (kB < P_N) {
      const float v2 = fmaxf(zzi + lpp[kB] - 2.0f * GTi[kB] +
                             TWO_EPS * (szi - lsp[kB]) + ZEPS2, 0.0f);
      if (v2 < v1) { v1 = v2; i1 = kB; }
    }
#pragma unroll
    for (int off = 1; off < 64; off <<= 1) {
      const float ov = __shfl_xor(v1, off, 64);
      const int oi = __shfl_xor(i1, off, 64);
      if (ov < v1 || (ov == v1 && oi < i1)) { v1 = ov; i1 = oi; }
    }
    const int p = i1;

    // step b: hardest positive in same-class suffix (w-gather)
    const float cp = lpp[p] + TWO_EPS * lsp[p] + ZEPS2;
    const int n = cnt[cls];
    const int* __restrict__ bk = bkt + cls * BCAP;
    float best = -INFINITY;
    int bestj = 0x7fffffff;
    for (int t = lane; t < n; t += 64) {
      const int jj = bk[t];
      if (jj >= i) {
        const float vv = fmaxf(cp + w[jj] - 2.0f * GT[(size_t)jj * GT_S + p], 0.0f);
        if (vv > best || (vv == best && jj < bestj)) { best = vv; bestj = jj; }
      }
    }
#pragma unroll
    for (int off = 1; off < 64; off <<= 1) {
      const float ov = __shfl_xor(best, off, 64);
      const int oj = __shfl_xor(bestj, off, 64);
      if (ov > best || (ov == best && oj < bestj)) { best = ov; bestj = oj; }
    }
    const float Dp = sqrtf(best);
    const int jp = bestj;

    // step c: logsumexp(-D_n) over proxies
    const float zzj = zz[jp], szj = sz[jp];
    const float* __restrict__ GTj = GT + (size_t)jp * GT_S;
    const float d1 = sqrtf(fmaxf(zzj + lpp[lane] - 2.0f * GTj[lane] +
                                 TWO_EPS * (szj - lsp[lane]) + ZEPS2, 0.0f));
    float d2 = INFINITY;
    if (kB < P_N)
      d2 = sqrtf(fmaxf(zzj + lpp[kB] - 2.0f * GTj[kB] +
                       TWO_EPS * (szj - lsp[kB]) + ZEPS2, 0.0f));
    const float mn = wave_min(fminf(d1, d2));
    float ss = expf(mn - d1) + ((kB < P_N) ? expf(mn - d2) : 0.0f);
    ss = wave_sum(ss);
    loss = Dp - mn + logf(ss);
  }
  if (lane == 0) part[wv] = (wid < A_N) ? loss : 0.0f;
  __syncthreads();

  // finalize (hierarchical counters; 683 = 16*42 + 11)
  if (wv == 0) {
    int last = 0;
    if (lane == 0) {
      AT_ST(&partial[b], part[0] + part[1] + part[2] + part[3]);
      __builtin_amdgcn_s_waitcnt(0);       // store completed at LLC
      const int sub = b & 15;              // residues 0..10: 43; 11..15: 42
      const unsigned quota = (sub < 11) ? 43u : 42u;
      const unsigned old = AT_ADDU(&ctr[sub * 32], 1u);
      if (old == quota - 1u) {
        const unsigned so = AT_ADDU(&ctr[16 * 32], 1u);
        if (so == 15u) last = 1;
      }
    }
    last = __shfl(last, 0, 64);
    if (last) {                            // one wave reduces 683 partials
      float s = 0.0f;
#pragma unroll
      for (int r = 0; r < 11; ++r) {
        const int t = lane + r * 64;
        if (t < NPART) s += AT_LD(&partial[t]);
      }
      s = wave_sum(s);
      if (lane == 0) out[0] = s * (1.0f / (float)A_N);
    }
  }
}

extern "C" void kernel_launch(void* const* d_in, const int* in_sizes, int n_in,
                              void* d_out, int out_size, void* d_ws, size_t ws_size,
                              hipStream_t stream) {
  const float* z = (const float*)d_in[0];      // [8192,128] f32
  const int* y_idx = (const int*)d_in[1];      // [8192] i32
  const float* prox = (const float*)d_in[2];   // [93,128] f32
  const int* y_map = (const int*)d_in[3];      // [62] i32
  float* out = (float*)d_out;

  // workspace layout (bytes), ~5.4 MB
  char* ws = (char*)d_ws;
  unsigned int* ctr = (unsigned int*)(ws + 0); // 17 counters, 128B stride
  float* pp    = (float*)(ws + 2560);          // 93*4 (pad 512)
  float* sp    = (float*)(ws + 3072);          // -> 3584
  float* zz    = (float*)(ws + 3584);          // 8192*4 -> 36352
  float* sz    = (float*)(ws + 36352);         // -> 69120
  float* w     = (float*)(ws + 69120);         // -> 101888
  int*   cnt   = (int*)  (ws + 101888);        // 62*4 (pad 256) -> 102144
  int*   bkt   = (int*)  (ws + 102144);        // 62*256*4 -> 165632
  float* parts = (float*)(ws + 165632);        // 683*4 (pad) -> 168448
  float* GT    = (float*)(ws + 168448);        // 8192*96*4 -> 3314176
  unsigned short* zb = (unsigned short*)(ws + 3314176);  // 8192*128*2 -> 5411328
  unsigned short* pb = (unsigned short*)(ws + 5411328);  // 96*128*2 -> 5435904

  kPrep<<<256 + NCLS + 1, 256, 0, stream>>>(z, y_idx, prox, y_map, zb, pb,
                                            pp, sp, zz, sz, w, cnt, bkt, ctr);
  kGT<<<B_N / 16, 64, 0, stream>>>(zb, pb, GT);
  kB2<<<NPART, 256, 0, stream>>>(y_idx, y_map, pp, sp, zz, sz, w,
                                 cnt, bkt, GT, parts, ctr, out);
}